// Round 7
// baseline (402.484 us; speedup 1.0000x reference)
//
#include <hip/hip_runtime.h>

#define NN 20000
#define NE 640000
#define DIM 128
#define ND (NN * DIM)

typedef float f32x4 __attribute__((ext_vector_type(4)));
typedef __bf16 bf16x8 __attribute__((ext_vector_type(8)));
typedef unsigned int u32;
typedef unsigned short u16;
typedef u32 u32x4 __attribute__((ext_vector_type(4)));

// sigma-stash addressing (u32 words, [64][128]): rotate cols by 8 per 4-row
// group -> exactly 2 lanes/bank on both the epilogue write and reduce read.
__device__ __forceinline__ int sgaddr(int row, int col) {
  return row * DIM + ((col + ((row & 12) << 1)) & 127);
}
// pack two f32 (truncating ->bf16) into one u32: lo16=bf16(a), hi16=bf16(b)
__device__ __forceinline__ u32 pk_bf16(float a, float b) {
  return __builtin_amdgcn_perm(__float_as_uint(b), __float_as_uint(a), 0x07060302u);
}
__device__ __forceinline__ float bf16_lo(u32 w) { return __uint_as_float(w << 16); }
__device__ __forceinline__ float bf16_hi(u32 w) { return __uint_as_float(w & 0xffff0000u); }
__device__ __forceinline__ float b2f(u16 v) { return __uint_as_float(((u32)v) << 16); }

union AFrag { bf16x8 b; u32x4 u; };

// ---------------------------------------------------------------------------
// prep_hist: blocks [0,2500): histogram of dst. blocks [2500,2540): pack all
// 5 weight matrices (Wa,Wb,Wd,We,Wc) f32 -> bf16 in MFMA fragment order:
// chunk (ks*8+nt)*64+lane holds W[nt*16+(lane&15)][ks*32+(lane>>4)*8 .. +8].
// block 2540: BN fold.
// ---------------------------------------------------------------------------
__global__ void prep_hist(const int* __restrict__ dst, int* __restrict__ cur,
                          const float* __restrict__ Wa, const float* __restrict__ Wb,
                          const float* __restrict__ Wd, const float* __restrict__ We,
                          const float* __restrict__ Wc, __bf16* __restrict__ wpack,
                          const float* __restrict__ gh, const float* __restrict__ bh,
                          const float* __restrict__ mh, const float* __restrict__ vh,
                          const float* __restrict__ ge, const float* __restrict__ be_,
                          const float* __restrict__ me, const float* __restrict__ ve,
                          float* __restrict__ bn) {
  int b = blockIdx.x;
  int tid = threadIdx.x;
  if (b < 2500) {                            // hist: 2500*256 == NE exactly
    atomicAdd(cur + dst[b * 256 + tid], 1);
    return;
  }
  b -= 2500;
  if (b < 40) {
    int t = b * 256 + tid;                   // < 10240 chunks (5 matrices)
    int m = t >> 11;                         // 0..4
    int chunk = t & 2047;
    int lane = chunk & 63, nt = (chunk >> 6) & 7, ks = chunk >> 9;
    int lq = lane >> 4, lm = lane & 15;
    const float* W = (m == 0) ? Wa : (m == 1) ? Wb : (m == 2) ? Wd
                   : (m == 3) ? We : Wc;
    const float* srcp = W + (nt * 16 + lm) * DIM + ks * 32 + lq * 8;
    bf16x8 v;
#pragma unroll
    for (int j = 0; j < 8; ++j) v[j] = (__bf16)srcp[j];
    *(bf16x8*)(wpack + (size_t)t * 8) = v;
  } else {                                   // b == 40: BN fold
    if (tid < DIM) {
      float sc = gh[tid] * rsqrtf(vh[tid] + 1e-5f);
      bn[tid] = sc;
      bn[DIM + tid] = bh[tid] - mh[tid] * sc;
    } else {
      int c = tid - DIM;
      float sc = ge[c] * rsqrtf(ve[c] + 1e-5f);
      bn[2 * DIM + c] = sc;
      bn[3 * DIM + c] = be_[c] - me[c] * sc;
    }
  }
}

// ---------------------------------------------------------------------------
// scan (1 block, int4) -> scatter
// ---------------------------------------------------------------------------
__global__ __launch_bounds__(1024) void scan20k(int* __restrict__ cur) {
  __shared__ int wsum[16];
  int tid = threadIdx.x, wid = tid >> 6, lane = tid & 63;
  int carry = 0;
  for (int base = 0; base < NN; base += 4096) {
    int idx = base + tid * 4;
    int4 v = {0, 0, 0, 0};
    if (idx < NN) v = *(const int4*)(cur + idx);
    int sum = v.x + v.y + v.z + v.w;
    int x = sum;
#pragma unroll
    for (int d = 1; d < 64; d <<= 1) {
      int y = __shfl_up(x, d, 64);
      if (lane >= d) x += y;
    }
    if (lane == 63) wsum[wid] = x;
    __syncthreads();
    if (tid < 16) {
      int s = wsum[tid];
#pragma unroll
      for (int d = 1; d < 16; d <<= 1) {
        int y = __shfl_up(s, d, 64);
        if (tid >= d) s += y;
      }
      wsum[tid] = s;
    }
    __syncthreads();
    int excl = carry + ((wid > 0) ? wsum[wid - 1] : 0) + x - sum;
    if (idx < NN) {
      int4 o;
      o.x = excl; o.y = excl + v.x; o.z = o.y + v.y; o.w = o.z + v.z;
      *(int4*)(cur + idx) = o;
    }
    carry += wsum[15];
    __syncthreads();
  }
}

__global__ void scatter(const int* __restrict__ dst, int* __restrict__ cur,
                        int* __restrict__ perm) {
  int e = blockIdx.x * 256 + threadIdx.x;
  if (e < NE) {
    int p = atomicAdd(cur + dst[e], 1);
    perm[p] = e;
  }
}

// ---------------------------------------------------------------------------
// node_gemm: barrier-free, 0 LDS. grid = tiles*4; block (tile,m) computes one
// output matrix tile; A-fragments loaded directly from global h (per-lane
// row=lm, k-slice=lq: 4 lq lanes cover one 128B line per instruction).
// m: 0 -> Ah (f32, +ba), 1 -> Bhb (+bb), 2 -> Dhb (+bd+bc), 3 -> Ehb (+be)
// ---------------------------------------------------------------------------
__global__ __launch_bounds__(256) void node_gemm(
    const float* __restrict__ h, const __bf16* __restrict__ wpack,
    const float* __restrict__ ba, const float* __restrict__ bb,
    const float* __restrict__ bd, const float* __restrict__ be,
    const float* __restrict__ bc,
    float* __restrict__ Ah, __bf16* __restrict__ Bhb,
    __bf16* __restrict__ Dhb, __bf16* __restrict__ Ehb) {
  const int tid = threadIdx.x;
  const int m = blockIdx.x & 3;
  const int row0 = (blockIdx.x >> 2) * 64;
  const int wv = tid >> 6, lane = tid & 63;
  const int lq = lane >> 4, lm = lane & 15;
  const int arow = row0 + wv * 16 + lm;
  const bf16x8* wp = (const bf16x8*)(wpack + (size_t)m * DIM * DIM);

  f32x4 acc[8];
#pragma unroll
  for (int i = 0; i < 8; ++i) acc[i] = (f32x4){0.f, 0.f, 0.f, 0.f};
  const float* pA = h + (size_t)arow * DIM;
#pragma unroll
  for (int ks = 0; ks < 4; ++ks) {
    int k0 = ks * 32 + lq * 8;
    f32x4 v0 = (f32x4){0.f, 0.f, 0.f, 0.f}, v1 = v0;
    if (arow < NN) {
      v0 = *(const f32x4*)(pA + k0);
      v1 = *(const f32x4*)(pA + k0 + 4);
    }
    AFrag A;
    A.u[0] = pk_bf16(v0[0], v0[1]);
    A.u[1] = pk_bf16(v0[2], v0[3]);
    A.u[2] = pk_bf16(v1[0], v1[1]);
    A.u[3] = pk_bf16(v1[2], v1[3]);
#pragma unroll
    for (int nt = 0; nt < 8; ++nt) {
      bf16x8 bfr = wp[(ks * 8 + nt) * 64 + lane];
      acc[nt] = __builtin_amdgcn_mfma_f32_16x16x32_bf16(A.b, bfr, acc[nt], 0, 0, 0);
    }
  }

  const float* bias = (m == 0) ? ba : (m == 1) ? bb : (m == 2) ? bd : be;
#pragma unroll
  for (int nt = 0; nt < 8; ++nt) {
    int col = nt * 16 + lm;
    float bv = bias[col];
    if (m == 2) bv += bc[col];
#pragma unroll
    for (int r = 0; r < 4; ++r) {
      int grow = row0 + wv * 16 + lq * 4 + r;
      if (grow < NN) {
        float val = acc[nt][r] + bv;
        if (m == 0) Ah[grow * DIM + col] = val;
        else if (m == 1) Bhb[grow * DIM + col] = (__bf16)val;
        else if (m == 2) Dhb[grow * DIM + col] = (__bf16)val;
        else Ehb[grow * DIM + col] = (__bf16)val;
      }
    }
  }
}

// ---------------------------------------------------------------------------
// edge_gemm (dst-sorted, BARRIER-FREE): each wave owns 16 sorted edges
// end-to-end. A-frags direct from global e[perm]; Ce += (Dh+bc)[src]+Eh[dst];
// e_out[perm] = relu(BN(x)); sigma/sigma*B packed u32 to wave-private LDS;
// wave-local 16-row segmented reduce (dst hoisted to SGPR via shfl ->
// wave-uniform branches), exclusive segments use plain stores.
// ---------------------------------------------------------------------------
__global__ __launch_bounds__(256, 4) void edge_gemm(
    const float* __restrict__ e, const __bf16* __restrict__ wcp,
    const int* __restrict__ src, const int* __restrict__ dst,
    const int* __restrict__ perm,
    const __bf16* __restrict__ Bhb, const __bf16* __restrict__ Dhb,
    const __bf16* __restrict__ Ehb,
    float* __restrict__ num, float* __restrict__ den,
    float* __restrict__ e_out, const float* __restrict__ bn) {
  __shared__ u32 sgp[64 * DIM];              // exactly 32 KB
  const int tid = threadIdx.x;
  const int wv = tid >> 6, lane = tid & 63;
  const int lq = lane >> 4, lm = lane & 15;
  const int e0 = blockIdx.x * 64;
  const int R0 = wv * 16;
  const int lrb = R0 + lq * 4;

  // per-lane indices (redundant loads; L1/L2 broadcast, no barrier needed)
  int pa = perm[e0 + R0 + lm];               // A-row for this lane's lm
  int pr[4], sA[4], dA[4];
#pragma unroll
  for (int r4 = 0; r4 < 4; ++r4) pr[r4] = perm[e0 + lrb + r4];
#pragma unroll
  for (int r4 = 0; r4 < 4; ++r4) {
    sA[r4] = src[pr[r4]];
    dA[r4] = dst[pr[r4]];
  }

  // GEMM: A direct from global (row=lm, k-slice=lq), B from packed Wc
  f32x4 acc[8];
#pragma unroll
  for (int i = 0; i < 8; ++i) acc[i] = (f32x4){0.f, 0.f, 0.f, 0.f};
  const bf16x8* wp = (const bf16x8*)wcp;
  const float* pA = e + (size_t)pa * DIM;
#pragma unroll
  for (int ks = 0; ks < 4; ++ks) {
    int k0 = ks * 32 + lq * 8;
    f32x4 v0 = __builtin_nontemporal_load((const f32x4*)(pA + k0));
    f32x4 v1 = __builtin_nontemporal_load((const f32x4*)(pA + k0 + 4));
    AFrag A;
    A.u[0] = pk_bf16(v0[0], v0[1]);
    A.u[1] = pk_bf16(v0[2], v0[3]);
    A.u[2] = pk_bf16(v1[0], v1[1]);
    A.u[3] = pk_bf16(v1[2], v1[3]);
#pragma unroll
    for (int nt = 0; nt < 8; ++nt) {
      bf16x8 bfr = wp[(ks * 8 + nt) * 64 + lane];
      acc[nt] = __builtin_amdgcn_mfma_f32_16x16x32_bf16(A.b, bfr, acc[nt], 0, 0, 0);
    }
  }

  // per-column BN constants (col = nt*16 + lm)
  float scv[8], shv[8];
#pragma unroll
  for (int nt = 0; nt < 8; ++nt) {
    scv[nt] = bn[2 * DIM + nt * 16 + lm];
    shv[nt] = bn[3 * DIM + nt * 16 + lm];
  }

  // epilogue: gathers + sigmoid + BN/ReLU store + sigma stash (wave-private)
  const u16* Du = (const u16*)Dhb;
  const u16* Eu = (const u16*)Ehb;
  const u16* Bu = (const u16*)Bhb;
#pragma unroll
  for (int r4 = 0; r4 < 4; ++r4) {
    const int lrow = lrb + r4;
    const u16* pD = Du + sA[r4] * DIM + lm;
    const u16* pE = Eu + dA[r4] * DIM + lm;
    const u16* pB = Bu + sA[r4] * DIM + lm;
    float* pO = e_out + (size_t)pr[r4] * DIM + lm;
#pragma unroll
    for (int nt = 0; nt < 8; ++nt) {
      float x = acc[nt][r4] + b2f(pD[nt * 16]) + b2f(pE[nt * 16]);
      float sig = __builtin_amdgcn_rcpf(1.0f + __expf(-x));
      float sb = sig * b2f(pB[nt * 16]);
      __builtin_nontemporal_store(fmaxf(scv[nt] * x + shv[nt], 0.0f),
                                  pO + nt * 16);
      sgp[sgaddr(lrow, nt * 16 + lm)] = pk_bf16(sig, sb);
    }
  }

  // wave-local segmented reduce: rows R0..R0+15, lane handles cols lane,lane+64
  {
    const int c0 = lane, c1 = lane + 64;
    float an0 = 0.f, ad0 = 0.f, an1 = 0.f, ad1 = 0.f;
    int prev = __shfl(dA[0], 0, 64);
    int seg_start = 0;
#pragma unroll
    for (int k = 0; k < 16; ++k) {
      int d = __shfl(dA[k & 3], (k >> 2) << 4, 64);   // dst of row R0+k (uniform)
      if (d != prev) {
        if (seg_start > 0) {               // segment fully inside chunk
          num[prev * DIM + c0] = an0; den[prev * DIM + c0] = ad0;
          num[prev * DIM + c1] = an1; den[prev * DIM + c1] = ad1;
        } else {
          atomicAdd(num + prev * DIM + c0, an0); atomicAdd(den + prev * DIM + c0, ad0);
          atomicAdd(num + prev * DIM + c1, an1); atomicAdd(den + prev * DIM + c1, ad1);
        }
        an0 = ad0 = an1 = ad1 = 0.f;
        prev = d; seg_start = k;
      }
      u32 w0 = sgp[sgaddr(R0 + k, c0)];
      u32 w1 = sgp[sgaddr(R0 + k, c1)];
      ad0 += bf16_lo(w0); an0 += bf16_hi(w0);
      ad1 += bf16_lo(w1); an1 += bf16_hi(w1);
    }
    atomicAdd(num + prev * DIM + c0, an0); atomicAdd(den + prev * DIM + c0, ad0);
    atomicAdd(num + prev * DIM + c1, an1); atomicAdd(den + prev * DIM + c1, ad1);
  }
}

// ---------------------------------------------------------------------------
// final_h: h_out = relu(BN_h(Ah + num/(den+1e-6)))
// ---------------------------------------------------------------------------
__global__ void final_h(const float* __restrict__ Ah, const float* __restrict__ num,
                        const float* __restrict__ den, const float* __restrict__ bn,
                        float* __restrict__ h_out) {
  int g = blockIdx.x * blockDim.x + threadIdx.x;
  int idx = g * 4;
  int col = idx & (DIM - 1);
  f32x4 a = *(const f32x4*)(Ah + idx);
  f32x4 n = *(const f32x4*)(num + idx);
  f32x4 d = *(const f32x4*)(den + idx);
  f32x4 o;
#pragma unroll
  for (int j = 0; j < 4; ++j) {
    float hn = a[j] + n[j] * __builtin_amdgcn_rcpf(d[j] + 1e-6f);
    o[j] = fmaxf(bn[col + j] * hn + bn[DIM + col + j], 0.0f);
  }
  *(f32x4*)(h_out + idx) = o;
}

// ---------------------------------------------------------------------------
extern "C" void kernel_launch(void* const* d_in, const int* in_sizes, int n_in,
                              void* d_out, int out_size, void* d_ws, size_t ws_size,
                              hipStream_t stream) {
  (void)in_sizes; (void)n_in; (void)out_size; (void)ws_size;
  const float* h   = (const float*)d_in[0];
  const float* e   = (const float*)d_in[1];
  const int*   src = (const int*)d_in[2];
  const int*   dst = (const int*)d_in[3];
  const float* Wa  = (const float*)d_in[4];
  const float* ba  = (const float*)d_in[5];
  const float* Wb  = (const float*)d_in[6];
  const float* bb  = (const float*)d_in[7];
  const float* Wc  = (const float*)d_in[8];
  const float* bc  = (const float*)d_in[9];
  const float* Wd  = (const float*)d_in[10];
  const float* bd  = (const float*)d_in[11];
  const float* We  = (const float*)d_in[12];
  const float* be  = (const float*)d_in[13];
  const float* gamma_h = (const float*)d_in[14];
  const float* beta_h  = (const float*)d_in[15];
  const float* mean_h  = (const float*)d_in[16];
  const float* var_h   = (const float*)d_in[17];
  const float* gamma_e = (const float*)d_in[18];
  const float* beta_e  = (const float*)d_in[19];
  const float* mean_e  = (const float*)d_in[20];
  const float* var_e   = (const float*)d_in[21];

  float* ws  = (float*)d_ws;
  float* Ah  = ws;                                // ND f32
  float* num = Ah + ND;                           // ND f32
  float* den = num + ND;                          // ND f32
  __bf16* Bhb = (__bf16*)(den + ND);              // ND bf16
  __bf16* Dhb = Bhb + ND;                         // ND bf16 (holds Dh+bd+bc)
  __bf16* Ehb = Dhb + ND;                         // ND bf16
  __bf16* wpack = Ehb + ND;                       // 5*DIM*DIM bf16 (frag order)
  float* bn  = (float*)(wpack + 5 * DIM * DIM);   // 4*DIM f32
  int*   cur = (int*)(bn + 4 * DIM);              // NN ints
  int*   perm = cur + NN;                         // NE ints

  float* h_out = (float*)d_out;
  float* e_out = h_out + ND;

  hipMemsetAsync(num, 0, (size_t)2 * ND * sizeof(float), stream);
  hipMemsetAsync(cur, 0, (size_t)NN * sizeof(int), stream);
  prep_hist<<<2541, 256, 0, stream>>>(dst, cur, Wa, Wb, Wd, We, Wc, wpack,
                                      gamma_h, beta_h, mean_h, var_h,
                                      gamma_e, beta_e, mean_e, var_e, bn);
  scan20k<<<1, 1024, 0, stream>>>(cur);
  scatter<<<NE / 256, 256, 0, stream>>>(dst, cur, perm);
  node_gemm<<<((NN + 63) / 64) * 4, 256, 0, stream>>>(h, wpack, ba, bb, bd, be, bc,
                                                      Ah, Bhb, Dhb, Ehb);
  edge_gemm<<<NE / 64, 256, 0, stream>>>(e, wpack + 4 * DIM * DIM, src, dst, perm,
                                         Bhb, Dhb, Ehb, num, den, e_out, bn);
  final_h<<<ND / 4 / 256, 256, 0, stream>>>(Ah, num, den, bn, h_out);
}